// Round 6
// baseline (217.566 us; speedup 1.0000x reference)
//
#include <hip/hip_runtime.h>
#include <hip/hip_bf16.h>
#include <math.h>

#define NB 64        // B
#define NH 8         // H
#define DKH 32       // DK
#define NE 65536     // E
#define ND 256       // N2
#define IDX_STRIDE 2048
#define SLICE 256    // keys per slice block
#define NSLICE 8     // SLICE*NSLICE = IDX_STRIDE

// ============ prep: q_b = Wq gq_b + bq ; t[h] = Wk_h^T q_h ; c[h] = q_h . bk_h
__global__ __launch_bounds__(256) void prep_k(const float* __restrict__ gq,
    const float* __restrict__ Wq, const float* __restrict__ bq,
    const float* __restrict__ Wk, const float* __restrict__ bk,
    float* __restrict__ t_ws, float* __restrict__ c_ws)
{
  __shared__ float xs[ND];
  __shared__ float qs[ND];
  const int b = blockIdx.x;
  const int j = threadIdx.x;
  xs[j] = gq[(size_t)b * ND + j];
  __syncthreads();
  float acc = bq[j];
  const float4* wp = (const float4*)(Wq + (size_t)j * ND);
  #pragma unroll 8
  for (int k4 = 0; k4 < ND / 4; ++k4) {
    float4 w = wp[k4];
    float4 x = *(const float4*)&xs[k4 * 4];
    acc = fmaf(x.x, w.x, acc);
    acc = fmaf(x.y, w.y, acc);
    acc = fmaf(x.z, w.z, acc);
    acc = fmaf(x.w, w.w, acc);
  }
  qs[j] = acc;
  __syncthreads();
  #pragma unroll
  for (int h = 0; h < NH; ++h) {
    float t = 0.f;
    #pragma unroll 8
    for (int dd = 0; dd < DKH; ++dd)
      t = fmaf(qs[h * DKH + dd], Wk[(size_t)(h * DKH + dd) * ND + j], t);
    t_ws[((size_t)b * NH + h) * ND + j] = t;
  }
  if (j < NH) {
    float c = 0.f;
    #pragma unroll
    for (int dd = 0; dd < DKH; ++dd)
      c = fmaf(qs[j * DKH + dd], bk[j * DKH + dd], c);
    c_ws[b * NH + j] = c;
  }
}

// ============ bucket: stable stream-compaction, per-b index lists (R3-validated)
__global__ __launch_bounds__(512) void bucket_k(const int* __restrict__ batch,
    int* __restrict__ idx, int* __restrict__ counts)
{
  __shared__ int wbase[8];
  __shared__ int running;
  const int b = blockIdx.x;
  const int tid = threadIdx.x;
  const int wid = tid >> 6, lane = tid & 63;
  const unsigned long long lt = (1ULL << lane) - 1ULL;
  if (tid == 0) running = 0;
  int* __restrict__ myidx = idx + b * IDX_STRIDE;

  for (int it = 0; it < NE / 2048; ++it) {
    const int e0 = it * 2048 + tid * 4;
    const int4 bt = *(const int4*)(batch + e0);
    const bool f[4] = {bt.x == b, bt.y == b, bt.z == b, bt.w == b};
    int rk[4];
    int wcnt = 0;
    #pragma unroll
    for (int u = 0; u < 4; ++u) {
      unsigned long long mk = __ballot(f[u]);
      rk[u] = wcnt + __popcll(mk & lt);
      wcnt += __popcll(mk);
    }
    __syncthreads();
    if (lane == 0) wbase[wid] = wcnt;
    __syncthreads();
    if (tid == 0) {
      int r = running;
      #pragma unroll
      for (int w = 0; w < 8; ++w) { int c = wbase[w]; wbase[w] = r; r += c; }
      running = r;
    }
    __syncthreads();
    const int base = wbase[wid];
    #pragma unroll
    for (int u = 0; u < 4; ++u) {
      const int p = base + rk[u];
      if (f[u] && p < IDX_STRIDE) myidx[p] = e0 + u;
    }
  }
  __syncthreads();
  if (tid == 0) counts[b] = running;
}

// ============ pass A: scores for one (b, slice) + per-slice max (reads local_key)
__global__ __launch_bounds__(256) void score_k(const float* __restrict__ lk,
    const int* __restrict__ idx, const int* __restrict__ counts,
    const float* __restrict__ t_ws, const float* __restrict__ c_ws,
    float* __restrict__ score_ws, float* __restrict__ m_ws)
{
  __shared__ float t_l[NH][260];
  __shared__ float x_t[32][260];
  __shared__ float s_t[NH][33];
  __shared__ float c_l[NH];
  __shared__ float mh[NH];

  const int s = blockIdx.x & 7;
  const int b = blockIdx.x >> 3;
  const int tid = threadIdx.x;

  const int count = min(counts[b], IDX_STRIDE);
  const int j0 = s * SLICE;
  const int jn = min(count - j0, SLICE);       // may be <= 0

  #pragma unroll
  for (int h = 0; h < NH; ++h)
    t_l[h][tid] = t_ws[((size_t)b * NH + h) * ND + tid];
  if (tid < NH) {
    c_l[tid] = c_ws[b * NH + tid];
    mh[tid] = -INFINITY;
  }

  const int ntile = (jn > 0) ? (jn + 31) / 32 : 0;
  const int key = tid >> 3, hh = tid & 7;
  const int xr = tid >> 3, xseg = tid & 7;

  for (int t = 0; t < ntile; ++t) {
    const int nk = min(32, jn - t * 32);
    __syncthreads();                               // (A) prev consumers done
    if (xr < nk) {
      const int e = idx[b * IDX_STRIDE + j0 + t * 32 + xr];
      const float4* xp = (const float4*)(lk + (size_t)e * ND + xseg * 32);
      #pragma unroll
      for (int u = 0; u < 8; ++u) {
        float4 v = xp[u];
        x_t[xr][xseg * 32 + 4 * u + 0] = v.x;
        x_t[xr][xseg * 32 + 4 * u + 1] = v.y;
        x_t[xr][xseg * 32 + 4 * u + 2] = v.z;
        x_t[xr][xseg * 32 + 4 * u + 3] = v.w;
      }
    }
    __syncthreads();                               // (B) x_t ready

    float sc = -INFINITY;
    if (key < nk) {
      float a0 = c_l[hh], a1 = 0.f, a2 = 0.f, a3 = 0.f;
      #pragma unroll 16
      for (int d4 = 0; d4 < 64; ++d4) {
        float4 tv = *(const float4*)&t_l[hh][4 * d4];
        float4 xv = *(const float4*)&x_t[key][4 * d4];
        a0 = fmaf(tv.x, xv.x, a0);
        a1 = fmaf(tv.y, xv.y, a1);
        a2 = fmaf(tv.z, xv.z, a2);
        a3 = fmaf(tv.w, xv.w, a3);
      }
      sc = (a0 + a1) + (a2 + a3);
    }
    s_t[hh][key] = sc;
    __syncthreads();                               // (C) s_t ready

    {
      const int h2 = tid >> 5, k2 = tid & 31;
      if (k2 < nk)
        score_ws[((size_t)b * NH + h2) * IDX_STRIDE + j0 + t * 32 + k2] = s_t[h2][k2];
    }
    if (tid < NH) {
      float mt = mh[tid];
      #pragma unroll
      for (int k2 = 0; k2 < 32; ++k2) mt = fmaxf(mt, s_t[tid][k2]);
      mh[tid] = mt;
    }
  }

  __syncthreads();
  if (tid < NH) m_ws[((size_t)b * NSLICE + s) * NH + tid] = mh[tid];
}

// ============ pass B: per b, combine M over slices + exact denominator
__global__ __launch_bounds__(256) void norm_k(const float* __restrict__ score_ws,
    const float* __restrict__ m_ws, const int* __restrict__ counts,
    float* __restrict__ Minv_ws)
{
  __shared__ float sM[NH];
  __shared__ float red[NH][264];
  const int b = blockIdx.x;
  const int tid = threadIdx.x;

  if (tid < NH) {
    float M = -INFINITY;
    #pragma unroll
    for (int s = 0; s < NSLICE; ++s)
      M = fmaxf(M, m_ws[((size_t)b * NSLICE + s) * NH + tid]);
    sM[tid] = M;
  }
  __syncthreads();

  const int count = min(counts[b], IDX_STRIDE);
  float ps[NH];
  #pragma unroll
  for (int h = 0; h < NH; ++h) ps[h] = 0.f;
  for (int j = tid; j < count; j += 256) {
    #pragma unroll
    for (int h = 0; h < NH; ++h)
      ps[h] += __expf(score_ws[((size_t)b * NH + h) * IDX_STRIDE + j] - sM[h]);
  }
  #pragma unroll
  for (int h = 0; h < NH; ++h) red[h][tid] = ps[h];
  __syncthreads();
  if (tid < NH) {
    float L = 0.f;
    for (int k = 0; k < 256; ++k) L += red[tid][k];
    Minv_ws[((size_t)b * NH + tid) * 2 + 0] = sM[tid];
    Minv_ws[((size_t)b * NH + tid) * 2 + 1] = (L > 0.f) ? 1.f / L : 0.f;
  }
}

// ============ pass C: dense coalesced attn-row writer
__global__ __launch_bounds__(256) void attn_write_k(
    const float* __restrict__ score_ws, const float* __restrict__ Minv_ws,
    const int* __restrict__ idx, const int* __restrict__ counts,
    float* __restrict__ attn_out)
{
  __shared__ float buf[1024];
  const int hb = blockIdx.x;          // h*64 + b
  const int h = hb >> 6, b = hb & 63;
  const int tid = threadIdx.x;
  const int count = min(counts[b], IDX_STRIDE);

  const float M = Minv_ws[((size_t)b * NH + h) * 2 + 0];
  const float inv = Minv_ws[((size_t)b * NH + h) * 2 + 1];

  const float* __restrict__ srow = score_ws + ((size_t)b * NH + h) * IDX_STRIDE;
  const int* __restrict__ myidx = idx + b * IDX_STRIDE;
  float* __restrict__ arow = attn_out + (size_t)hb * NE;

  int jlo = 0;
  for (int c = 0; c < NE / 1024; ++c) {
    *(float4*)&buf[tid * 4] = (float4){0.f, 0.f, 0.f, 0.f};
    __syncthreads();
    const int ehi = (c + 1) * 1024;
    int lo = jlo, hi = count;
    while (lo < hi) {
      const int mid = (lo + hi) >> 1;
      if (myidx[mid] < ehi) lo = mid + 1; else hi = mid;
    }
    const int jhi = lo;
    for (int j = jlo + tid; j < jhi; j += 256)
      buf[myidx[j] - c * 1024] = __expf(srow[j] - M) * inv;
    __syncthreads();
    *(float4*)(arow + c * 1024 + tid * 4) = *(float4*)&buf[tid * 4];
    jlo = jhi;
  }
}

// ============ pass D: exact-weight aggregate per (b, slice) — gathers
// local_VALUE rows (scores use local_key; output uses local_value!)
__global__ __launch_bounds__(256) void agg_k(const float* __restrict__ lv,
    const int* __restrict__ idx, const int* __restrict__ counts,
    const float* __restrict__ score_ws, const float* __restrict__ Minv_ws,
    float* __restrict__ pagg_ws)
{
  __shared__ float w_t[NH][260];
  __shared__ float x_t[32][260];

  const int s = blockIdx.x & 7;
  const int b = blockIdx.x >> 3;
  const int tid = threadIdx.x;

  const int count = min(counts[b], IDX_STRIDE);
  const int j0 = s * SLICE;
  const int jn = min(count - j0, SLICE);

  #pragma unroll
  for (int h = 0; h < NH; ++h) {
    float w = 0.f;
    if (tid < jn) {
      const float M = Minv_ws[((size_t)b * NH + h) * 2 + 0];
      const float inv = Minv_ws[((size_t)b * NH + h) * 2 + 1];
      w = __expf(score_ws[((size_t)b * NH + h) * IDX_STRIDE + j0 + tid] - M) * inv;
    }
    w_t[h][tid] = w;
  }

  float acc8[NH];
  #pragma unroll
  for (int h = 0; h < NH; ++h) acc8[h] = 0.f;

  const int ntile = (jn > 0) ? (jn + 31) / 32 : 0;
  const int xr = tid >> 3, xseg = tid & 7;

  __syncthreads();                                 // w_t ready
  for (int t = 0; t < ntile; ++t) {
    const int nk = min(32, jn - t * 32);
    if (xr < nk) {
      const int e = idx[b * IDX_STRIDE + j0 + t * 32 + xr];
      const float4* xp = (const float4*)(lv + (size_t)e * ND + xseg * 32);
      #pragma unroll
      for (int u = 0; u < 8; ++u) {
        float4 v = xp[u];
        x_t[xr][xseg * 32 + 4 * u + 0] = v.x;
        x_t[xr][xseg * 32 + 4 * u + 1] = v.y;
        x_t[xr][xseg * 32 + 4 * u + 2] = v.z;
        x_t[xr][xseg * 32 + 4 * u + 3] = v.w;
      }
    }
    __syncthreads();                               // x_t ready
    for (int k2 = 0; k2 < nk; ++k2) {
      const float xv = x_t[k2][tid];
      #pragma unroll
      for (int h = 0; h < NH; ++h)
        acc8[h] = fmaf(w_t[h][t * 32 + k2], xv, acc8[h]);
    }
    __syncthreads();                               // consumers done before restage
  }

  #pragma unroll
  for (int h = 0; h < NH; ++h)
    pagg_ws[(((size_t)b * NSLICE + s) * NH + h) * ND + tid] = acc8[h];
}

// ============ pass E: sum slices, apply Wv (+bv), then Wo (+bo)
__global__ __launch_bounds__(256) void final_k(const float* __restrict__ pagg_ws,
    const int* __restrict__ counts, const float* __restrict__ Wv,
    const float* __restrict__ bv, const float* __restrict__ Wo,
    const float* __restrict__ bo, float* __restrict__ xout)
{
  __shared__ float agg[NH][260];
  __shared__ float opre[ND];
  const int b = blockIdx.x;
  const int tid = threadIdx.x;

  #pragma unroll
  for (int h = 0; h < NH; ++h) {
    float a = 0.f;
    #pragma unroll
    for (int s = 0; s < NSLICE; ++s)
      a += pagg_ws[(((size_t)b * NSLICE + s) * NH + h) * ND + tid];
    agg[h][tid] = a;
  }
  const float ind = (counts[b] > 0) ? 1.f : 0.f;
  __syncthreads();

  {
    const int h = tid >> 5;
    float acc = bv[tid] * ind;
    const float4* wp = (const float4*)(Wv + (size_t)tid * ND);
    #pragma unroll 8
    for (int d4 = 0; d4 < ND / 4; ++d4) {
      float4 w = wp[d4];
      float4 g = *(const float4*)&agg[h][4 * d4];
      acc = fmaf(w.x, g.x, acc);
      acc = fmaf(w.y, g.y, acc);
      acc = fmaf(w.z, g.z, acc);
      acc = fmaf(w.w, g.w, acc);
    }
    opre[tid] = acc;
  }
  __syncthreads();
  {
    float acc = bo[tid];
    const float4* wp = (const float4*)(Wo + (size_t)tid * ND);
    #pragma unroll 8
    for (int d4 = 0; d4 < ND / 4; ++d4) {
      float4 w = wp[d4];
      float4 g = *(const float4*)&opre[4 * d4];
      acc = fmaf(w.x, g.x, acc);
      acc = fmaf(w.y, g.y, acc);
      acc = fmaf(w.z, g.z, acc);
      acc = fmaf(w.w, g.w, acc);
    }
    xout[(size_t)b * ND + tid] = acc;
  }
}

extern "C" void kernel_launch(void* const* d_in, const int* in_sizes, int n_in,
                              void* d_out, int out_size, void* d_ws, size_t ws_size,
                              hipStream_t stream)
{
  const float* gq   = (const float*)d_in[0];
  const float* lk   = (const float*)d_in[1];
  const float* lv   = (const float*)d_in[2];
  const int*  batch = (const int*)d_in[3];
  const float* Wq = (const float*)d_in[4];
  const float* bq = (const float*)d_in[5];
  const float* Wk = (const float*)d_in[6];
  const float* bk = (const float*)d_in[7];
  const float* Wv = (const float*)d_in[8];
  const float* bv = (const float*)d_in[9];
  const float* Wo = (const float*)d_in[10];
  const float* bo = (const float*)d_in[11];

  float* xout = (float*)d_out;                          // [64,256]
  float* attn_out = xout + (size_t)NB * ND;             // [H,B,E]

  float* t_ws     = (float*)d_ws;                                   // 131072
  float* c_ws     = t_ws + (size_t)NB * NH * ND;                    // 512
  float* score_ws = c_ws + (size_t)NB * NH;                         // 1048576
  float* m_ws     = score_ws + (size_t)NB * NH * IDX_STRIDE;        // 4096
  float* Minv_ws  = m_ws + (size_t)NB * NSLICE * NH;                // 1024
  float* pagg_ws  = Minv_ws + (size_t)NB * NH * 2;                  // 1048576
  int*   idx      = (int*)(pagg_ws + (size_t)NB * NSLICE * NH * ND);// 131072
  int*   counts   = idx + (size_t)NB * IDX_STRIDE;                  // 64

  prep_k<<<NB, ND, 0, stream>>>(gq, Wq, bq, Wk, bk, t_ws, c_ws);
  bucket_k<<<NB, 512, 0, stream>>>(batch, idx, counts);
  score_k<<<NB * NSLICE, 256, 0, stream>>>(lk, idx, counts, t_ws, c_ws,
                                           score_ws, m_ws);
  norm_k<<<NB, 256, 0, stream>>>(score_ws, m_ws, counts, Minv_ws);
  attn_write_k<<<NH * NB, 256, 0, stream>>>(score_ws, Minv_ws, idx, counts, attn_out);
  agg_k<<<NB * NSLICE, 256, 0, stream>>>(lv, idx, counts, score_ws, Minv_ws, pagg_ws);
  final_k<<<NB, 256, 0, stream>>>(pagg_ws, counts, Wv, bv, Wo, bo, xout);
}